// Round 12
// baseline (163.773 us; speedup 1.0000x reference)
//
#include <hip/hip_runtime.h>
#include <stdint.h>

#define NPTS 262144
#define TBL 524288u
#define TBL_MASK 524287u
#define NBINS 32768

/* ---- workspace layout (bytes) ---- */
#define WS_TAB_OFF   0u
#define WS_TAB_BYTES (16u * 524288u * 4u)            /* 33,554,432 */
#define WS_ENC_OFF   WS_TAB_BYTES
#define WS_ENC_BYTES (16u * (uint32_t)NPTS * 4u)     /* 16,777,216 */
#define WS_W_OFF     (WS_ENC_OFF + WS_ENC_BYTES)
#define WS_W_U32     4736
#define WS_HIST_OFF  (WS_W_OFF + WS_W_U32 * 4u)
#define WS_KEY_OFF   (WS_HIST_OFF + NBINS * 4u)
#define WS_IDX_OFF   (WS_KEY_OFF + (uint32_t)NPTS * 4u)
#define WS_PS_OFF    (WS_IDX_OFF + (uint32_t)NPTS * 4u)
#define WS_DS_OFF    (WS_PS_OFF + (uint32_t)NPTS * 12u)
#define WS_NEED_SORT ((size_t)WS_DS_OFF + (size_t)NPTS * 12u)
#define WS_NEED      ((size_t)WS_HIST_OFF)           /* unsorted path */

/* packed-weight u32 offsets */
#define PW_D1 0
#define PW_D2 1024
#define PW_C1 1536
#define PW_C2 2560
#define PW_C3 4608

typedef __attribute__((ext_vector_type(8))) _Float16 half8;
typedef __attribute__((ext_vector_type(4))) float f32x4;

__device__ const float d_scale[16] = {16.f, 21.f, 27.f, 36.f, 48.f, 64.f, 84.f, 111.f,
                                      147.f, 194.f, 256.f, 337.f, 445.f, 588.f, 776.f, 1024.f};

__device__ __forceinline__ uint16_t f2h(float f) {
    _Float16 h = (_Float16)f;
    return __builtin_bit_cast(uint16_t, h);
}
__device__ __forceinline__ uint32_t pack2(float lo, float hi) {
    return (uint32_t)f2h(lo) | ((uint32_t)f2h(hi) << 16);
}
__device__ __forceinline__ float h2f_lo(uint32_t v) {
    return (float)__builtin_bit_cast(_Float16, (uint16_t)(v & 0xffffu));
}
__device__ __forceinline__ float h2f_hi(uint32_t v) {
    return (float)__builtin_bit_cast(_Float16, (uint16_t)(v >> 16));
}

__device__ __forceinline__ half8 bfrag_p(const uint32_t* __restrict__ Wp, int N, int kofs, int nofs, int l) {
    const int kp0 = (kofs + ((l >> 4) << 3)) >> 1;
    const uint32_t* p = Wp + (size_t)kp0 * N + (nofs + (l & 15));
    union { uint32_t u[4]; half8 s; } r;
    r.u[0] = p[0 * N];
    r.u[1] = p[1 * N];
    r.u[2] = p[2 * N];
    r.u[3] = p[3 * N];
    return r.s;
}
__device__ __forceinline__ half8 bfrag3_p(const uint32_t* __restrict__ Wp, int kofs, int l) {
    const int kp0 = (kofs + ((l >> 4) << 3)) >> 1;
    const int n = l & 15;
    union { uint32_t u[4]; half8 s; } r;
    if (n < 3) {
        const uint32_t* p = Wp + (size_t)kp0 * 4 + n;
        r.u[0] = p[0]; r.u[1] = p[4]; r.u[2] = p[8]; r.u[3] = p[12];
    } else {
        r.u[0] = 0; r.u[1] = 0; r.u[2] = 0; r.u[3] = 0;
    }
    return r.s;
}

__device__ __forceinline__ half8 ld_a_h(const unsigned char* hcb, int mt, int kb, int l) {
    const int row = mt * 16 + (l & 15);
    uint32_t byte = (uint32_t)row * 128 + (uint32_t)kb * 64 + (uint32_t)((l >> 4) << 4);
    byte ^= (uint32_t)(row & 7) << 4;
    return *(const half8*)(hcb + byte);
}
__device__ __forceinline__ void st_h(unsigned char* hcb, int row, int col, float v) {
    uint32_t byte = (uint32_t)row * 128 + (uint32_t)col * 2;
    byte ^= (uint32_t)(row & 7) << 4;
    *(uint16_t*)(hcb + byte) = f2h(fmaxf(v, 0.f));
}

#define MFMA(a, b, c) __builtin_amdgcn_mfma_f32_16x16x32_f16((a), (b), (c), 0, 0, 0)

__device__ __forceinline__ uint32_t spread3(uint32_t x) {
    x &= 0x3FFu;
    x = (x | (x << 16)) & 0x030000FFu;
    x = (x | (x << 8))  & 0x0300F00Fu;
    x = (x | (x << 4))  & 0x030C30C3u;
    x = (x | (x << 2))  & 0x09249249u;
    return x;
}

// ================= khist: Morton keys + histogram =================
__global__ void __launch_bounds__(256) khist(
    const float* __restrict__ g_pos, uint32_t* __restrict__ key, uint32_t* __restrict__ hist)
{
    const int p = blockIdx.x * 256 + threadIdx.x;
    const float px = g_pos[3 * p + 0];
    const float py = g_pos[3 * p + 1];
    const float pz = g_pos[3 * p + 2];
    const uint32_t cx = min(31u, (uint32_t)(px * 32.f));
    const uint32_t cy = min(31u, (uint32_t)(py * 32.f));
    const uint32_t cz = min(31u, (uint32_t)(pz * 32.f));
    const uint32_t k = spread3(cx) | (spread3(cy) << 1) | (spread3(cz) << 2);
    key[p] = k;
    atomicAdd(&hist[k], 1u);
}

// ================= kscan: single pass, 1024 threads x 32 bins each =================
__global__ void __launch_bounds__(1024) kscan(uint32_t* __restrict__ hist) {
    const int tid = threadIdx.x;
    const int lane = tid & 63, wid = tid >> 6;     // 16 waves
    uint4* hp = (uint4*)(hist + tid * 32);
    uint4 a[8];
    #pragma unroll
    for (int i = 0; i < 8; ++i) a[i] = hp[i];
    uint32_t S = 0;
    #pragma unroll
    for (int i = 0; i < 8; ++i) S += a[i].x + a[i].y + a[i].z + a[i].w;

    uint32_t s = S;
    #pragma unroll
    for (int d = 1; d < 64; d <<= 1) {
        const uint32_t t = __shfl_up(s, d);
        if (lane >= d) s += t;
    }
    __shared__ uint32_t ws[16];
    if (lane == 63) ws[wid] = s;
    __syncthreads();
    uint32_t woff = 0;
    for (int w = 0; w < wid; ++w) woff += ws[w];
    uint32_t run = woff + (s - S);                 // global exclusive base

    #pragma unroll
    for (int i = 0; i < 8; ++i) {
        uint4 v = a[i];
        uint4 o;
        o.x = run; run += v.x;
        o.y = run; run += v.y;
        o.z = run; run += v.z;
        o.w = run; run += v.w;
        hp[i] = o;
    }
}

// ====== convert_scatter: blocks [0,SB) scatter (latency-bound, dispatched first);
//        blocks [SB, SB+8192) table fp32->fp16 + weight pack (BW-bound) — co-scheduled ======
__global__ void __launch_bounds__(256) convert_scatter(
    const float4* __restrict__ t, uint4* __restrict__ o,
    const float* __restrict__ wd1, const float* __restrict__ wd2,
    const float* __restrict__ wc1, const float* __restrict__ wc2,
    const float* __restrict__ wc3, uint32_t* __restrict__ wp,
    const float* __restrict__ g_pos, const float* __restrict__ g_dir,
    const uint32_t* __restrict__ key,
    uint32_t* __restrict__ hist, uint32_t* __restrict__ out_idx,
    float* __restrict__ pos_sorted, float* __restrict__ dir_sorted,
    const int scatter_blocks)
{
    const int blk = blockIdx.x;
    if (blk < scatter_blocks) {
        const int p = blk * 256 + threadIdx.x;
        const uint32_t slot = atomicAdd(&hist[key[p]], 1u);
        out_idx[slot] = (uint32_t)p;
        pos_sorted[3 * slot + 0] = g_pos[3 * p + 0];
        pos_sorted[3 * slot + 1] = g_pos[3 * p + 1];
        pos_sorted[3 * slot + 2] = g_pos[3 * p + 2];
        dir_sorted[3 * slot + 0] = g_dir[3 * p + 0];
        dir_sorted[3 * slot + 1] = g_dir[3 * p + 1];
        dir_sorted[3 * slot + 2] = g_dir[3 * p + 2];
    } else {
        const int cb = blk - scatter_blocks;
        const int i = cb * 256 + threadIdx.x;
        const float4 a = t[2 * i];
        const float4 b = t[2 * i + 1];
        o[i] = make_uint4(pack2(a.x, a.y), pack2(a.z, a.w),
                          pack2(b.x, b.y), pack2(b.z, b.w));
        if (cb == 0) {
            const int tid = threadIdx.x;
            for (int j = tid; j < 1024; j += 256) {
                const int kp = j >> 6, n = j & 63;
                wp[PW_D1 + j] = pack2(wd1[(2 * kp) * 64 + n], wd1[(2 * kp + 1) * 64 + n]);
            }
            for (int j = tid; j < 512; j += 256) {
                const int kp = j >> 4, n = j & 15;
                wp[PW_D2 + j] = pack2(wd2[(2 * kp) * 16 + n], wd2[(2 * kp + 1) * 16 + n]);
            }
            for (int j = tid; j < 1024; j += 256) {
                const int kp = j >> 6, n = j & 63;
                wp[PW_C1 + j] = pack2(wc1[(2 * kp) * 64 + n], wc1[(2 * kp + 1) * 64 + n]);
            }
            for (int j = tid; j < 2048; j += 256) {
                const int kp = j >> 6, n = j & 63;
                wp[PW_C2 + j] = pack2(wc2[(2 * kp) * 64 + n], wc2[(2 * kp + 1) * 64 + n]);
            }
            for (int j = tid; j < 128; j += 256) {
                const int kp = j >> 2, n = j & 3;
                wp[PW_C3 + j] = (n < 3) ? pack2(wc3[(2 * kp) * 3 + n], wc3[(2 * kp + 1) * 3 + n]) : 0u;
            }
        }
    }
}

// ============ gather: level-phased, 2 points/thread, XCD-pinned levels (x, 15-x) ============
__global__ void __launch_bounds__(256) gather_enc2(
    const float* __restrict__ pos,
    const uint32_t* __restrict__ tab16,
    uint32_t* __restrict__ enc)
{
    const int b = blockIdx.x;                       // 8192 blocks
    const int x8 = b & 7;                           // XCD hint
    const int lev = (b >> 12) ? (15 - x8) : x8;     // XCD x: levels x and 15-x
    const int pbase = (((b >> 3) & 511) << 9) + threadIdx.x;

    const float s = d_scale[lev];
    const uint32_t* t = tab16 + (size_t)lev * TBL;

    float tx[2], ty[2], tz[2];
    uint32_t idx0[2][4], idx1[2][4];
    bool odd[2];
    #pragma unroll
    for (int q = 0; q < 2; ++q) {
        const int p = pbase + q * 256;
        const float px = pos[3 * p + 0];
        const float py = pos[3 * p + 1];
        const float pz = pos[3 * p + 2];
        const float sx = px * s, sy = py * s, sz = pz * s;
        const float fx = floorf(sx), fy = floorf(sy), fz = floorf(sz);
        tx[q] = sx - fx; ty[q] = sy - fy; tz[q] = sz - fz;
        const uint32_t x0 = (uint32_t)fx, x1 = (uint32_t)ceilf(sx);
        const uint32_t hy0 = (uint32_t)fy * 2654435761u, hy1 = (uint32_t)ceilf(sy) * 2654435761u;
        const uint32_t hz0 = (uint32_t)fz * 805459861u,  hz1 = (uint32_t)ceilf(sz) * 805459861u;
        odd[q] = (x0 & 1u) != 0u;
        #pragma unroll
        for (int cp = 0; cp < 4; ++cp) {
            const uint32_t hyz = ((cp & 1) ? hy1 : hy0) ^ ((cp & 2) ? hz1 : hz0);
            idx0[q][cp] = (x0 ^ hyz) & TBL_MASK;
            idx1[q][cp] = (x1 ^ hyz) & TBL_MASK;
        }
    }
    uint2 v2[2][4];
    #pragma unroll
    for (int q = 0; q < 2; ++q)
        #pragma unroll
        for (int cp = 0; cp < 4; ++cp)
            v2[q][cp] = *reinterpret_cast<const uint2*>(t + (idx0[q][cp] & ~1u));
    uint32_t fup[2][4];
    #pragma unroll
    for (int q = 0; q < 2; ++q)
        #pragma unroll
        for (int cp = 0; cp < 4; ++cp)
            fup[q][cp] = odd[q] ? t[idx1[q][cp]] : 0u;
    #pragma unroll
    for (int q = 0; q < 2; ++q) {
        float e0 = 0.f, e1 = 0.f;
        #pragma unroll
        for (int cp = 0; cp < 4; ++cp) {
            const bool lo = (idx0[q][cp] & 1u) == 0u;
            const uint32_t v0 = lo ? v2[q][cp].x : v2[q][cp].y;
            uint32_t v1 = lo ? v2[q][cp].y : v2[q][cp].x;
            if (odd[q]) v1 = fup[q][cp];
            const float wyz = ((cp & 1) ? ty[q] : 1.f - ty[q]) * ((cp & 2) ? tz[q] : 1.f - tz[q]);
            const float w0 = (1.f - tx[q]) * wyz;
            const float w1 = tx[q] * wyz;
            e0 = fmaf(h2f_lo(v0), w0, fmaf(h2f_lo(v1), w1, e0));
            e1 = fmaf(h2f_hi(v0), w0, fmaf(h2f_hi(v1), w1, e1));
        }
        enc[(size_t)lev * NPTS + pbase + q * 256] = pack2(e0, e1);
    }
}

// ============================ MLP (MFMA, packed fp16 weights) ============================
__global__ void __launch_bounds__(256, 3) nerf_mlp(
    const float* __restrict__ g_dir,       // sorted when use_perm
    const uint32_t* __restrict__ enc,
    const uint32_t* __restrict__ wp,
    const uint32_t* __restrict__ out_idx,
    const int use_perm,
    const float* __restrict__ g_bd1,
    const float* __restrict__ g_bd2,
    const float* __restrict__ g_bc1,
    const float* __restrict__ g_bc2,
    const float* __restrict__ g_bc3,
    float* __restrict__ g_out)
{
    __shared__ __align__(16) unsigned char s_lds[4 * 12288];
    unsigned char* wbase = s_lds + (threadIdx.x >> 6) * 12288;
    unsigned char* hcb  = wbase;
    unsigned char* xinb = wbase + 8192;

    const int l = threadIdx.x & 63;
    const int m_my = l >> 4;
    const int r_my = l & 15;
    const int wpt  = blockIdx.x * 256 + (threadIdx.x & 192);
    const int p    = wpt + l;

    #pragma unroll
    for (int kb = 0; kb < 4; ++kb) {
        uint4 w4;
        w4.x = enc[(size_t)(4 * kb + 0) * NPTS + p];
        w4.y = enc[(size_t)(4 * kb + 1) * NPTS + p];
        w4.z = enc[(size_t)(4 * kb + 2) * NPTS + p];
        w4.w = enc[(size_t)(4 * kb + 3) * NPTS + p];
        *(uint4*)(hcb + m_my * 1024 + (kb * 16 + r_my) * 16) = w4;
    }

    const float dx = g_dir[3 * p + 0];
    const float dy = g_dir[3 * p + 1];
    const float dz = g_dir[3 * p + 2];

    {
        const float xx = dx * dx, yy = dy * dy, zz = dz * dz;
        float s[16];
        s[0]  = 0.28209479177387814f;
        s[1]  = 0.4886025119029199f * dy;
        s[2]  = 0.4886025119029199f * dz;
        s[3]  = 0.4886025119029199f * dx;
        s[4]  = 1.0925484305920792f * dx * dy;
        s[5]  = 1.0925484305920792f * dy * dz;
        s[6]  = 0.9461746957575601f * zz - 0.31539156525252f;
        s[7]  = 1.0925484305920792f * dx * dz;
        s[8]  = 0.5462742152960396f * (xx - yy);
        s[9]  = 0.5900435899266435f * dy * (3.f * xx - yy);
        s[10] = 2.890611442640554f * dx * dy * dz;
        s[11] = 0.4570457994644658f * dy * (5.f * zz - 1.f);
        s[12] = 0.3731763325901154f * dz * (5.f * zz - 3.f);
        s[13] = 0.4570457994644658f * dx * (5.f * zz - 1.f);
        s[14] = 1.445305721320277f * dz * (xx - yy);
        s[15] = 0.5900435899266435f * dx * (xx - 3.f * yy);
        *(uint4*)(xinb + m_my * 1024 + (32 + r_my) * 16) =
            make_uint4(pack2(s[0], s[1]), pack2(s[2], s[3]), pack2(s[4], s[5]), pack2(s[6], s[7]));
        *(uint4*)(xinb + m_my * 1024 + (48 + r_my) * 16) =
            make_uint4(pack2(s[8], s[9]), pack2(s[10], s[11]), pack2(s[12], s[13]), pack2(s[14], s[15]));
    }

    const int cl = l & 15;
    const int rg = (l >> 4) << 2;

    // L1
    {
        f32x4 acc[4][4];
        half8 B[4];
        #pragma unroll
        for (int nt = 0; nt < 4; ++nt) {
            B[nt] = bfrag_p(wp + PW_D1, 64, 0, nt * 16, l);
            const float b = g_bd1[nt * 16 + cl];
            #pragma unroll
            for (int mt = 0; mt < 4; ++mt) acc[mt][nt] = (f32x4){b, b, b, b};
        }
        #pragma unroll
        for (int mt = 0; mt < 4; ++mt) {
            const half8 A = *(const half8*)(hcb + mt * 1024 + l * 16);
            #pragma unroll
            for (int nt = 0; nt < 4; ++nt) acc[mt][nt] = MFMA(A, B[nt], acc[mt][nt]);
        }
        #pragma unroll
        for (int mt = 0; mt < 4; ++mt)
            #pragma unroll
            for (int nt = 0; nt < 4; ++nt)
                #pragma unroll
                for (int r = 0; r < 4; ++r)
                    st_h(hcb, mt * 16 + rg + r, nt * 16 + cl, acc[mt][nt][r]);
    }

    // L2 -> density out + xin kb 0,1
    {
        const half8 B0 = bfrag_p(wp + PW_D2, 16, 0,  0, l);
        const half8 B1 = bfrag_p(wp + PW_D2, 16, 32, 0, l);
        const float b = g_bd2[cl];
        #pragma unroll
        for (int mt = 0; mt < 4; ++mt) {
            f32x4 acc = (f32x4){b, b, b, b};
            acc = MFMA(ld_a_h(hcb, mt, 0, l), B0, acc);
            acc = MFMA(ld_a_h(hcb, mt, 1, l), B1, acc);
            #pragma unroll
            for (int r = 0; r < 4; ++r) {
                const int pt = wpt + mt * 16 + rg + r;
                const uint32_t opt = use_perm ? out_idx[pt] : (uint32_t)pt;
                g_out[(size_t)opt * 16 + cl] = acc[r];
                const uint32_t byte = (uint32_t)mt * 1024
                                    + (uint32_t)(((cl >> 3) * 16 + rg + r) * 16) + (uint32_t)(cl & 7) * 2;
                *(uint16_t*)(xinb + byte) = f2h(acc[r]);
            }
        }
    }

    // L3
    {
        f32x4 acc[4][4];
        half8 B[4];
        #pragma unroll
        for (int nt = 0; nt < 4; ++nt) {
            B[nt] = bfrag_p(wp + PW_C1, 64, 0, nt * 16, l);
            const float b = g_bc1[nt * 16 + cl];
            #pragma unroll
            for (int mt = 0; mt < 4; ++mt) acc[mt][nt] = (f32x4){b, b, b, b};
        }
        #pragma unroll
        for (int mt = 0; mt < 4; ++mt) {
            const half8 A = *(const half8*)(xinb + mt * 1024 + l * 16);
            #pragma unroll
            for (int nt = 0; nt < 4; ++nt) acc[mt][nt] = MFMA(A, B[nt], acc[mt][nt]);
        }
        #pragma unroll
        for (int mt = 0; mt < 4; ++mt)
            #pragma unroll
            for (int nt = 0; nt < 4; ++nt)
                #pragma unroll
                for (int r = 0; r < 4; ++r)
                    st_h(hcb, mt * 16 + rg + r, nt * 16 + cl, acc[mt][nt][r]);
    }

    // L4
    {
        f32x4 acc[4][4];
        #pragma unroll
        for (int nt = 0; nt < 4; ++nt) {
            const float b = g_bc2[nt * 16 + cl];
            #pragma unroll
            for (int mt = 0; mt < 4; ++mt) acc[mt][nt] = (f32x4){b, b, b, b};
        }
        #pragma unroll
        for (int kb = 0; kb < 2; ++kb) {
            half8 A[4];
            #pragma unroll
            for (int mt = 0; mt < 4; ++mt) A[mt] = ld_a_h(hcb, mt, kb, l);
            #pragma unroll
            for (int nt = 0; nt < 4; ++nt) {
                const half8 B = bfrag_p(wp + PW_C2, 64, kb * 32, nt * 16, l);
                #pragma unroll
                for (int mt = 0; mt < 4; ++mt) acc[mt][nt] = MFMA(A[mt], B, acc[mt][nt]);
            }
        }
        #pragma unroll
        for (int mt = 0; mt < 4; ++mt)
            #pragma unroll
            for (int nt = 0; nt < 4; ++nt)
                #pragma unroll
                for (int r = 0; r < 4; ++r)
                    st_h(hcb, mt * 16 + rg + r, nt * 16 + cl, acc[mt][nt][r]);
    }

    // L5
    {
        const half8 B0 = bfrag3_p(wp + PW_C3, 0, l);
        const half8 B1 = bfrag3_p(wp + PW_C3, 32, l);
        const float b = (cl < 3) ? g_bc3[cl] : 0.f;
        #pragma unroll
        for (int mt = 0; mt < 4; ++mt) {
            f32x4 acc = (f32x4){b, b, b, b};
            acc = MFMA(ld_a_h(hcb, mt, 0, l), B0, acc);
            acc = MFMA(ld_a_h(hcb, mt, 1, l), B1, acc);
            if (cl < 3) {
                #pragma unroll
                for (int r = 0; r < 4; ++r) {
                    const int pt = wpt + mt * 16 + rg + r;
                    const uint32_t opt = use_perm ? out_idx[pt] : (uint32_t)pt;
                    g_out[(size_t)NPTS * 16 + (size_t)opt * 3 + cl] = 1.f / (1.f + expf(-acc[r]));
                }
            }
        }
    }
}

extern "C" void kernel_launch(void* const* d_in, const int* in_sizes, int n_in,
                              void* d_out, int out_size, void* d_ws, size_t ws_size,
                              hipStream_t stream) {
    uint32_t* tab16 = (uint32_t*)((char*)d_ws + WS_TAB_OFF);
    uint32_t* enc   = (uint32_t*)((char*)d_ws + WS_ENC_OFF);
    uint32_t* wpk   = (uint32_t*)((char*)d_ws + WS_W_OFF);
    uint32_t* hist  = (uint32_t*)((char*)d_ws + WS_HIST_OFF);
    uint32_t* key   = (uint32_t*)((char*)d_ws + WS_KEY_OFF);
    uint32_t* oidx  = (uint32_t*)((char*)d_ws + WS_IDX_OFF);
    float*    psort = (float*)((char*)d_ws + WS_PS_OFF);
    float*    dsort = (float*)((char*)d_ws + WS_DS_OFF);

    const float* g_pos = (const float*)d_in[0];
    const float* g_dir = (const float*)d_in[1];

    if (ws_size >= WS_NEED_SORT) {
        hipMemsetAsync(hist, 0, NBINS * 4, stream);
        khist<<<NPTS / 256, 256, 0, stream>>>(g_pos, key, hist);
        kscan<<<1, 1024, 0, stream>>>(hist);
        convert_scatter<<<1024 + 8192, 256, 0, stream>>>(
            (const float4*)d_in[2], (uint4*)tab16,
            (const float*)d_in[3], (const float*)d_in[5],
            (const float*)d_in[7], (const float*)d_in[9],
            (const float*)d_in[11], wpk,
            g_pos, g_dir, key, hist, oidx, psort, dsort, 1024);
        gather_enc2<<<8192, 256, 0, stream>>>(psort, tab16, enc);
        nerf_mlp<<<NPTS / 256, 256, 0, stream>>>(
            dsort, enc, wpk, oidx, 1,
            (const float*)d_in[4], (const float*)d_in[6],
            (const float*)d_in[8], (const float*)d_in[10],
            (const float*)d_in[12],
            (float*)d_out);
    } else {
        convert_scatter<<<8192, 256, 0, stream>>>(
            (const float4*)d_in[2], (uint4*)tab16,
            (const float*)d_in[3], (const float*)d_in[5],
            (const float*)d_in[7], (const float*)d_in[9],
            (const float*)d_in[11], wpk,
            g_pos, g_dir, nullptr, nullptr, nullptr, nullptr, nullptr, 0);
        gather_enc2<<<8192, 256, 0, stream>>>(g_pos, tab16, enc);
        nerf_mlp<<<NPTS / 256, 256, 0, stream>>>(
            g_dir, enc, wpk, nullptr, 0,
            (const float*)d_in[4], (const float*)d_in[6],
            (const float*)d_in[8], (const float*)d_in[10],
            (const float*)d_in[12],
            (float*)d_out);
    }
}

// Round 13
// 158.318 us; speedup vs baseline: 1.0345x; 1.0345x over previous
//
#include <hip/hip_runtime.h>
#include <stdint.h>

#define NPTS 262144
#define TBL 524288u
#define TBL_MASK 524287u
#define NBINS 32768

/* ---- workspace layout (bytes) ---- */
#define WS_TAB_OFF   0u
#define WS_TAB_BYTES (8u * 524288u * 4u)             /* fp16 slabs, levels 8-15 only */
#define WS_ENC_OFF   WS_TAB_BYTES
#define WS_ENC_BYTES (16u * (uint32_t)NPTS * 4u)     /* 16,777,216 */
#define WS_W_OFF     (WS_ENC_OFF + WS_ENC_BYTES)
#define WS_W_U32     4736
#define WS_HIST_OFF  (WS_W_OFF + WS_W_U32 * 4u)
#define WS_KEY_OFF   (WS_HIST_OFF + NBINS * 4u)
#define WS_IDX_OFF   (WS_KEY_OFF + (uint32_t)NPTS * 4u)
#define WS_PS_OFF    (WS_IDX_OFF + (uint32_t)NPTS * 4u)
#define WS_DS_OFF    (WS_PS_OFF + (uint32_t)NPTS * 12u)
#define WS_NEED_SORT ((size_t)WS_DS_OFF + (size_t)NPTS * 12u)
#define WS_NEED      ((size_t)WS_HIST_OFF)           /* unsorted path */

/* packed-weight u32 offsets */
#define PW_D1 0
#define PW_D2 1024
#define PW_C1 1536
#define PW_C2 2560
#define PW_C3 4608

typedef __attribute__((ext_vector_type(8))) _Float16 half8;
typedef __attribute__((ext_vector_type(4))) float f32x4;

__device__ const float d_scale[16] = {16.f, 21.f, 27.f, 36.f, 48.f, 64.f, 84.f, 111.f,
                                      147.f, 194.f, 256.f, 337.f, 445.f, 588.f, 776.f, 1024.f};

__device__ __forceinline__ uint16_t f2h(float f) {
    _Float16 h = (_Float16)f;
    return __builtin_bit_cast(uint16_t, h);
}
__device__ __forceinline__ uint32_t pack2(float lo, float hi) {
    return (uint32_t)f2h(lo) | ((uint32_t)f2h(hi) << 16);
}
__device__ __forceinline__ float h2f_lo(uint32_t v) {
    return (float)__builtin_bit_cast(_Float16, (uint16_t)(v & 0xffffu));
}
__device__ __forceinline__ float h2f_hi(uint32_t v) {
    return (float)__builtin_bit_cast(_Float16, (uint16_t)(v >> 16));
}

__device__ __forceinline__ half8 bfrag_p(const uint32_t* __restrict__ Wp, int N, int kofs, int nofs, int l) {
    const int kp0 = (kofs + ((l >> 4) << 3)) >> 1;
    const uint32_t* p = Wp + (size_t)kp0 * N + (nofs + (l & 15));
    union { uint32_t u[4]; half8 s; } r;
    r.u[0] = p[0 * N];
    r.u[1] = p[1 * N];
    r.u[2] = p[2 * N];
    r.u[3] = p[3 * N];
    return r.s;
}
__device__ __forceinline__ half8 bfrag3_p(const uint32_t* __restrict__ Wp, int kofs, int l) {
    const int kp0 = (kofs + ((l >> 4) << 3)) >> 1;
    const int n = l & 15;
    union { uint32_t u[4]; half8 s; } r;
    if (n < 3) {
        const uint32_t* p = Wp + (size_t)kp0 * 4 + n;
        r.u[0] = p[0]; r.u[1] = p[4]; r.u[2] = p[8]; r.u[3] = p[12];
    } else {
        r.u[0] = 0; r.u[1] = 0; r.u[2] = 0; r.u[3] = 0;
    }
    return r.s;
}

__device__ __forceinline__ half8 ld_a_h(const unsigned char* hcb, int mt, int kb, int l) {
    const int row = mt * 16 + (l & 15);
    uint32_t byte = (uint32_t)row * 128 + (uint32_t)kb * 64 + (uint32_t)((l >> 4) << 4);
    byte ^= (uint32_t)(row & 7) << 4;
    return *(const half8*)(hcb + byte);
}
__device__ __forceinline__ void st_h(unsigned char* hcb, int row, int col, float v) {
    uint32_t byte = (uint32_t)row * 128 + (uint32_t)col * 2;
    byte ^= (uint32_t)(row & 7) << 4;
    *(uint16_t*)(hcb + byte) = f2h(fmaxf(v, 0.f));
}

#define MFMA(a, b, c) __builtin_amdgcn_mfma_f32_16x16x32_f16((a), (b), (c), 0, 0, 0)

__device__ __forceinline__ uint32_t spread3(uint32_t x) {
    x &= 0x3FFu;
    x = (x | (x << 16)) & 0x030000FFu;
    x = (x | (x << 8))  & 0x0300F00Fu;
    x = (x | (x << 4))  & 0x030C30C3u;
    x = (x | (x << 2))  & 0x09249249u;
    return x;
}

// ================= khist: Morton keys + histogram =================
__global__ void __launch_bounds__(256) khist(
    const float* __restrict__ g_pos, uint32_t* __restrict__ key, uint32_t* __restrict__ hist)
{
    const int p = blockIdx.x * 256 + threadIdx.x;
    const float px = g_pos[3 * p + 0];
    const float py = g_pos[3 * p + 1];
    const float pz = g_pos[3 * p + 2];
    const uint32_t cx = min(31u, (uint32_t)(px * 32.f));
    const uint32_t cy = min(31u, (uint32_t)(py * 32.f));
    const uint32_t cz = min(31u, (uint32_t)(pz * 32.f));
    const uint32_t k = spread3(cx) | (spread3(cy) << 1) | (spread3(cz) << 2);
    key[p] = k;
    atomicAdd(&hist[k], 1u);
}

// ================= kscan: single pass, 1024 threads x 32 bins each =================
__global__ void __launch_bounds__(1024) kscan(uint32_t* __restrict__ hist) {
    const int tid = threadIdx.x;
    const int lane = tid & 63, wid = tid >> 6;     // 16 waves
    uint4* hp = (uint4*)(hist + tid * 32);
    uint4 a[8];
    #pragma unroll
    for (int i = 0; i < 8; ++i) a[i] = hp[i];
    uint32_t S = 0;
    #pragma unroll
    for (int i = 0; i < 8; ++i) S += a[i].x + a[i].y + a[i].z + a[i].w;

    uint32_t s = S;
    #pragma unroll
    for (int d = 1; d < 64; d <<= 1) {
        const uint32_t t = __shfl_up(s, d);
        if (lane >= d) s += t;
    }
    __shared__ uint32_t ws[16];
    if (lane == 63) ws[wid] = s;
    __syncthreads();
    uint32_t woff = 0;
    for (int w = 0; w < wid; ++w) woff += ws[w];
    uint32_t run = woff + (s - S);                 // global exclusive base

    #pragma unroll
    for (int i = 0; i < 8; ++i) {
        uint4 v = a[i];
        uint4 o;
        o.x = run; run += v.x;
        o.y = run; run += v.y;
        o.z = run; run += v.z;
        o.w = run; run += v.w;
        hp[i] = o;
    }
}

// ====== convert_scatter: blocks [0,SB) scatter; blocks [SB, SB+4096) convert
//        table levels 8-15 fp32->fp16 + weight pack (block SB) ======
__global__ void __launch_bounds__(256) convert_scatter(
    const float4* __restrict__ t8,                 /* = g_tab + 2*8*TBL floats */
    uint4* __restrict__ o,                         /* fp16 slabs, 8 levels */
    const float* __restrict__ wd1, const float* __restrict__ wd2,
    const float* __restrict__ wc1, const float* __restrict__ wc2,
    const float* __restrict__ wc3, uint32_t* __restrict__ wp,
    const float* __restrict__ g_pos, const float* __restrict__ g_dir,
    const uint32_t* __restrict__ key,
    uint32_t* __restrict__ hist, uint32_t* __restrict__ out_idx,
    float* __restrict__ pos_sorted, float* __restrict__ dir_sorted,
    const int scatter_blocks)
{
    const int blk = blockIdx.x;
    if (blk < scatter_blocks) {
        const int p = blk * 256 + threadIdx.x;
        const uint32_t slot = atomicAdd(&hist[key[p]], 1u);
        out_idx[slot] = (uint32_t)p;
        pos_sorted[3 * slot + 0] = g_pos[3 * p + 0];
        pos_sorted[3 * slot + 1] = g_pos[3 * p + 1];
        pos_sorted[3 * slot + 2] = g_pos[3 * p + 2];
        dir_sorted[3 * slot + 0] = g_dir[3 * p + 0];
        dir_sorted[3 * slot + 1] = g_dir[3 * p + 1];
        dir_sorted[3 * slot + 2] = g_dir[3 * p + 2];
    } else {
        const int cb = blk - scatter_blocks;       // 0..4095
        const int i = cb * 256 + threadIdx.x;      // 4 entries per thread
        const float4 a = t8[2 * i];
        const float4 b = t8[2 * i + 1];
        o[i] = make_uint4(pack2(a.x, a.y), pack2(a.z, a.w),
                          pack2(b.x, b.y), pack2(b.z, b.w));
        if (cb == 0) {
            const int tid = threadIdx.x;
            for (int j = tid; j < 1024; j += 256) {
                const int kp = j >> 6, n = j & 63;
                wp[PW_D1 + j] = pack2(wd1[(2 * kp) * 64 + n], wd1[(2 * kp + 1) * 64 + n]);
            }
            for (int j = tid; j < 512; j += 256) {
                const int kp = j >> 4, n = j & 15;
                wp[PW_D2 + j] = pack2(wd2[(2 * kp) * 16 + n], wd2[(2 * kp + 1) * 16 + n]);
            }
            for (int j = tid; j < 1024; j += 256) {
                const int kp = j >> 6, n = j & 63;
                wp[PW_C1 + j] = pack2(wc1[(2 * kp) * 64 + n], wc1[(2 * kp + 1) * 64 + n]);
            }
            for (int j = tid; j < 2048; j += 256) {
                const int kp = j >> 6, n = j & 63;
                wp[PW_C2 + j] = pack2(wc2[(2 * kp) * 64 + n], wc2[(2 * kp + 1) * 64 + n]);
            }
            for (int j = tid; j < 128; j += 256) {
                const int kp = j >> 2, n = j & 3;
                wp[PW_C3 + j] = (n < 3) ? pack2(wc3[(2 * kp) * 3 + n], wc3[(2 * kp + 1) * 3 + n]) : 0u;
            }
        }
    }
}

// ============ gather: level-phased, 2 points/thread, XCD-pinned levels (x, 15-x) ============
// Levels 0-7 read the fp32 input table directly (merge-cheap; no conversion needed);
// levels 8-15 read the fp16 slabs (2MB -> XCD-L2 resident, request-bound path).
__global__ void __launch_bounds__(256) gather_enc2(
    const float* __restrict__ pos,
    const float* __restrict__ g_tab32,
    const uint32_t* __restrict__ tab16,
    uint32_t* __restrict__ enc)
{
    const int b = blockIdx.x;                       // 8192 blocks
    const int x8 = b & 7;                           // XCD hint
    const int lev = (b >> 12) ? (15 - x8) : x8;     // XCD x: levels x and 15-x
    const int pbase = (((b >> 3) & 511) << 9) + threadIdx.x;

    const float s = d_scale[lev];

    float tx[2], ty[2], tz[2];
    uint32_t idx0[2][4], idx1[2][4];
    bool odd[2];
    #pragma unroll
    for (int q = 0; q < 2; ++q) {
        const int p = pbase + q * 256;
        const float px = pos[3 * p + 0];
        const float py = pos[3 * p + 1];
        const float pz = pos[3 * p + 2];
        const float sx = px * s, sy = py * s, sz = pz * s;
        const float fx = floorf(sx), fy = floorf(sy), fz = floorf(sz);
        tx[q] = sx - fx; ty[q] = sy - fy; tz[q] = sz - fz;
        const uint32_t x0 = (uint32_t)fx, x1 = (uint32_t)ceilf(sx);
        const uint32_t hy0 = (uint32_t)fy * 2654435761u, hy1 = (uint32_t)ceilf(sy) * 2654435761u;
        const uint32_t hz0 = (uint32_t)fz * 805459861u,  hz1 = (uint32_t)ceilf(sz) * 805459861u;
        odd[q] = (x0 & 1u) != 0u;
        #pragma unroll
        for (int cp = 0; cp < 4; ++cp) {
            const uint32_t hyz = ((cp & 1) ? hy1 : hy0) ^ ((cp & 2) ? hz1 : hz0);
            idx0[q][cp] = (x0 ^ hyz) & TBL_MASK;
            idx1[q][cp] = (x1 ^ hyz) & TBL_MASK;
        }
    }

    float e[2][2] = {{0.f, 0.f}, {0.f, 0.f}};
    if (lev >= 8) {
        const uint32_t* t = tab16 + (size_t)(lev - 8) * TBL;
        uint2 v2[2][4];
        #pragma unroll
        for (int q = 0; q < 2; ++q)
            #pragma unroll
            for (int cp = 0; cp < 4; ++cp)
                v2[q][cp] = *reinterpret_cast<const uint2*>(t + (idx0[q][cp] & ~1u));
        uint32_t fup[2][4];
        #pragma unroll
        for (int q = 0; q < 2; ++q)
            #pragma unroll
            for (int cp = 0; cp < 4; ++cp)
                fup[q][cp] = odd[q] ? t[idx1[q][cp]] : 0u;
        #pragma unroll
        for (int q = 0; q < 2; ++q) {
            #pragma unroll
            for (int cp = 0; cp < 4; ++cp) {
                const bool lo = (idx0[q][cp] & 1u) == 0u;
                const uint32_t v0 = lo ? v2[q][cp].x : v2[q][cp].y;
                uint32_t v1 = lo ? v2[q][cp].y : v2[q][cp].x;
                if (odd[q]) v1 = fup[q][cp];
                const float wyz = ((cp & 1) ? ty[q] : 1.f - ty[q]) * ((cp & 2) ? tz[q] : 1.f - tz[q]);
                const float w0 = (1.f - tx[q]) * wyz;
                const float w1 = tx[q] * wyz;
                e[q][0] = fmaf(h2f_lo(v0), w0, fmaf(h2f_lo(v1), w1, e[q][0]));
                e[q][1] = fmaf(h2f_hi(v0), w0, fmaf(h2f_hi(v1), w1, e[q][1]));
            }
        }
    } else {
        const float2* t = (const float2*)g_tab32 + (size_t)lev * TBL;
        float4 v2[2][4];
        #pragma unroll
        for (int q = 0; q < 2; ++q)
            #pragma unroll
            for (int cp = 0; cp < 4; ++cp)
                v2[q][cp] = *reinterpret_cast<const float4*>(t + (idx0[q][cp] & ~1u));
        float2 fup[2][4];
        #pragma unroll
        for (int q = 0; q < 2; ++q)
            #pragma unroll
            for (int cp = 0; cp < 4; ++cp)
                fup[q][cp] = odd[q] ? t[idx1[q][cp]] : make_float2(0.f, 0.f);
        #pragma unroll
        for (int q = 0; q < 2; ++q) {
            #pragma unroll
            for (int cp = 0; cp < 4; ++cp) {
                const bool lo = (idx0[q][cp] & 1u) == 0u;
                const float v0x = lo ? v2[q][cp].x : v2[q][cp].z;
                const float v0y = lo ? v2[q][cp].y : v2[q][cp].w;
                float v1x = lo ? v2[q][cp].z : v2[q][cp].x;
                float v1y = lo ? v2[q][cp].w : v2[q][cp].y;
                if (odd[q]) { v1x = fup[q][cp].x; v1y = fup[q][cp].y; }
                const float wyz = ((cp & 1) ? ty[q] : 1.f - ty[q]) * ((cp & 2) ? tz[q] : 1.f - tz[q]);
                const float w0 = (1.f - tx[q]) * wyz;
                const float w1 = tx[q] * wyz;
                e[q][0] = fmaf(v0x, w0, fmaf(v1x, w1, e[q][0]));
                e[q][1] = fmaf(v0y, w0, fmaf(v1y, w1, e[q][1]));
            }
        }
    }
    #pragma unroll
    for (int q = 0; q < 2; ++q)
        enc[(size_t)lev * NPTS + pbase + q * 256] = pack2(e[q][0], e[q][1]);
}

// ============================ MLP (MFMA, packed fp16 weights) ============================
__global__ void __launch_bounds__(256, 3) nerf_mlp(
    const float* __restrict__ g_dir,       // sorted when use_perm
    const uint32_t* __restrict__ enc,
    const uint32_t* __restrict__ wp,
    const uint32_t* __restrict__ out_idx,
    const int use_perm,
    const float* __restrict__ g_bd1,
    const float* __restrict__ g_bd2,
    const float* __restrict__ g_bc1,
    const float* __restrict__ g_bc2,
    const float* __restrict__ g_bc3,
    float* __restrict__ g_out)
{
    __shared__ __align__(16) unsigned char s_lds[4 * 12288];
    unsigned char* wbase = s_lds + (threadIdx.x >> 6) * 12288;
    unsigned char* hcb  = wbase;
    unsigned char* xinb = wbase + 8192;

    const int l = threadIdx.x & 63;
    const int m_my = l >> 4;
    const int r_my = l & 15;
    const int wpt  = blockIdx.x * 256 + (threadIdx.x & 192);
    const int p    = wpt + l;

    #pragma unroll
    for (int kb = 0; kb < 4; ++kb) {
        uint4 w4;
        w4.x = enc[(size_t)(4 * kb + 0) * NPTS + p];
        w4.y = enc[(size_t)(4 * kb + 1) * NPTS + p];
        w4.z = enc[(size_t)(4 * kb + 2) * NPTS + p];
        w4.w = enc[(size_t)(4 * kb + 3) * NPTS + p];
        *(uint4*)(hcb + m_my * 1024 + (kb * 16 + r_my) * 16) = w4;
    }

    const float dx = g_dir[3 * p + 0];
    const float dy = g_dir[3 * p + 1];
    const float dz = g_dir[3 * p + 2];

    {
        const float xx = dx * dx, yy = dy * dy, zz = dz * dz;
        float s[16];
        s[0]  = 0.28209479177387814f;
        s[1]  = 0.4886025119029199f * dy;
        s[2]  = 0.4886025119029199f * dz;
        s[3]  = 0.4886025119029199f * dx;
        s[4]  = 1.0925484305920792f * dx * dy;
        s[5]  = 1.0925484305920792f * dy * dz;
        s[6]  = 0.9461746957575601f * zz - 0.31539156525252f;
        s[7]  = 1.0925484305920792f * dx * dz;
        s[8]  = 0.5462742152960396f * (xx - yy);
        s[9]  = 0.5900435899266435f * dy * (3.f * xx - yy);
        s[10] = 2.890611442640554f * dx * dy * dz;
        s[11] = 0.4570457994644658f * dy * (5.f * zz - 1.f);
        s[12] = 0.3731763325901154f * dz * (5.f * zz - 3.f);
        s[13] = 0.4570457994644658f * dx * (5.f * zz - 1.f);
        s[14] = 1.445305721320277f * dz * (xx - yy);
        s[15] = 0.5900435899266435f * dx * (xx - 3.f * yy);
        *(uint4*)(xinb + m_my * 1024 + (32 + r_my) * 16) =
            make_uint4(pack2(s[0], s[1]), pack2(s[2], s[3]), pack2(s[4], s[5]), pack2(s[6], s[7]));
        *(uint4*)(xinb + m_my * 1024 + (48 + r_my) * 16) =
            make_uint4(pack2(s[8], s[9]), pack2(s[10], s[11]), pack2(s[12], s[13]), pack2(s[14], s[15]));
    }

    const int cl = l & 15;
    const int rg = (l >> 4) << 2;

    // L1
    {
        f32x4 acc[4][4];
        half8 B[4];
        #pragma unroll
        for (int nt = 0; nt < 4; ++nt) {
            B[nt] = bfrag_p(wp + PW_D1, 64, 0, nt * 16, l);
            const float b = g_bd1[nt * 16 + cl];
            #pragma unroll
            for (int mt = 0; mt < 4; ++mt) acc[mt][nt] = (f32x4){b, b, b, b};
        }
        #pragma unroll
        for (int mt = 0; mt < 4; ++mt) {
            const half8 A = *(const half8*)(hcb + mt * 1024 + l * 16);
            #pragma unroll
            for (int nt = 0; nt < 4; ++nt) acc[mt][nt] = MFMA(A, B[nt], acc[mt][nt]);
        }
        #pragma unroll
        for (int mt = 0; mt < 4; ++mt)
            #pragma unroll
            for (int nt = 0; nt < 4; ++nt)
                #pragma unroll
                for (int r = 0; r < 4; ++r)
                    st_h(hcb, mt * 16 + rg + r, nt * 16 + cl, acc[mt][nt][r]);
    }

    // L2 -> density out + xin kb 0,1
    {
        const half8 B0 = bfrag_p(wp + PW_D2, 16, 0,  0, l);
        const half8 B1 = bfrag_p(wp + PW_D2, 16, 32, 0, l);
        const float b = g_bd2[cl];
        #pragma unroll
        for (int mt = 0; mt < 4; ++mt) {
            f32x4 acc = (f32x4){b, b, b, b};
            acc = MFMA(ld_a_h(hcb, mt, 0, l), B0, acc);
            acc = MFMA(ld_a_h(hcb, mt, 1, l), B1, acc);
            #pragma unroll
            for (int r = 0; r < 4; ++r) {
                const int pt = wpt + mt * 16 + rg + r;
                const uint32_t opt = use_perm ? out_idx[pt] : (uint32_t)pt;
                g_out[(size_t)opt * 16 + cl] = acc[r];
                const uint32_t byte = (uint32_t)mt * 1024
                                    + (uint32_t)(((cl >> 3) * 16 + rg + r) * 16) + (uint32_t)(cl & 7) * 2;
                *(uint16_t*)(xinb + byte) = f2h(acc[r]);
            }
        }
    }

    // L3
    {
        f32x4 acc[4][4];
        half8 B[4];
        #pragma unroll
        for (int nt = 0; nt < 4; ++nt) {
            B[nt] = bfrag_p(wp + PW_C1, 64, 0, nt * 16, l);
            const float b = g_bc1[nt * 16 + cl];
            #pragma unroll
            for (int mt = 0; mt < 4; ++mt) acc[mt][nt] = (f32x4){b, b, b, b};
        }
        #pragma unroll
        for (int mt = 0; mt < 4; ++mt) {
            const half8 A = *(const half8*)(xinb + mt * 1024 + l * 16);
            #pragma unroll
            for (int nt = 0; nt < 4; ++nt) acc[mt][nt] = MFMA(A, B[nt], acc[mt][nt]);
        }
        #pragma unroll
        for (int mt = 0; mt < 4; ++mt)
            #pragma unroll
            for (int nt = 0; nt < 4; ++nt)
                #pragma unroll
                for (int r = 0; r < 4; ++r)
                    st_h(hcb, mt * 16 + rg + r, nt * 16 + cl, acc[mt][nt][r]);
    }

    // L4
    {
        f32x4 acc[4][4];
        #pragma unroll
        for (int nt = 0; nt < 4; ++nt) {
            const float b = g_bc2[nt * 16 + cl];
            #pragma unroll
            for (int mt = 0; mt < 4; ++mt) acc[mt][nt] = (f32x4){b, b, b, b};
        }
        #pragma unroll
        for (int kb = 0; kb < 2; ++kb) {
            half8 A[4];
            #pragma unroll
            for (int mt = 0; mt < 4; ++mt) A[mt] = ld_a_h(hcb, mt, kb, l);
            #pragma unroll
            for (int nt = 0; nt < 4; ++nt) {
                const half8 B = bfrag_p(wp + PW_C2, 64, kb * 32, nt * 16, l);
                #pragma unroll
                for (int mt = 0; mt < 4; ++mt) acc[mt][nt] = MFMA(A[mt], B, acc[mt][nt]);
            }
        }
        #pragma unroll
        for (int mt = 0; mt < 4; ++mt)
            #pragma unroll
            for (int nt = 0; nt < 4; ++nt)
                #pragma unroll
                for (int r = 0; r < 4; ++r)
                    st_h(hcb, mt * 16 + rg + r, nt * 16 + cl, acc[mt][nt][r]);
    }

    // L5
    {
        const half8 B0 = bfrag3_p(wp + PW_C3, 0, l);
        const half8 B1 = bfrag3_p(wp + PW_C3, 32, l);
        const float b = (cl < 3) ? g_bc3[cl] : 0.f;
        #pragma unroll
        for (int mt = 0; mt < 4; ++mt) {
            f32x4 acc = (f32x4){b, b, b, b};
            acc = MFMA(ld_a_h(hcb, mt, 0, l), B0, acc);
            acc = MFMA(ld_a_h(hcb, mt, 1, l), B1, acc);
            if (cl < 3) {
                #pragma unroll
                for (int r = 0; r < 4; ++r) {
                    const int pt = wpt + mt * 16 + rg + r;
                    const uint32_t opt = use_perm ? out_idx[pt] : (uint32_t)pt;
                    g_out[(size_t)NPTS * 16 + (size_t)opt * 3 + cl] = 1.f / (1.f + expf(-acc[r]));
                }
            }
        }
    }
}

extern "C" void kernel_launch(void* const* d_in, const int* in_sizes, int n_in,
                              void* d_out, int out_size, void* d_ws, size_t ws_size,
                              hipStream_t stream) {
    uint32_t* tab16 = (uint32_t*)((char*)d_ws + WS_TAB_OFF);
    uint32_t* enc   = (uint32_t*)((char*)d_ws + WS_ENC_OFF);
    uint32_t* wpk   = (uint32_t*)((char*)d_ws + WS_W_OFF);
    uint32_t* hist  = (uint32_t*)((char*)d_ws + WS_HIST_OFF);
    uint32_t* key   = (uint32_t*)((char*)d_ws + WS_KEY_OFF);
    uint32_t* oidx  = (uint32_t*)((char*)d_ws + WS_IDX_OFF);
    float*    psort = (float*)((char*)d_ws + WS_PS_OFF);
    float*    dsort = (float*)((char*)d_ws + WS_DS_OFF);

    const float* g_pos = (const float*)d_in[0];
    const float* g_dir = (const float*)d_in[1];
    const float* g_tab = (const float*)d_in[2];
    const float4* t8 = (const float4*)(g_tab + (size_t)2 * 8 * TBL);

    if (ws_size >= WS_NEED_SORT) {
        hipMemsetAsync(hist, 0, NBINS * 4, stream);
        khist<<<NPTS / 256, 256, 0, stream>>>(g_pos, key, hist);
        kscan<<<1, 1024, 0, stream>>>(hist);
        convert_scatter<<<1024 + 4096, 256, 0, stream>>>(
            t8, (uint4*)tab16,
            (const float*)d_in[3], (const float*)d_in[5],
            (const float*)d_in[7], (const float*)d_in[9],
            (const float*)d_in[11], wpk,
            g_pos, g_dir, key, hist, oidx, psort, dsort, 1024);
        gather_enc2<<<8192, 256, 0, stream>>>(psort, g_tab, tab16, enc);
        nerf_mlp<<<NPTS / 256, 256, 0, stream>>>(
            dsort, enc, wpk, oidx, 1,
            (const float*)d_in[4], (const float*)d_in[6],
            (const float*)d_in[8], (const float*)d_in[10],
            (const float*)d_in[12],
            (float*)d_out);
    } else {
        convert_scatter<<<4096, 256, 0, stream>>>(
            t8, (uint4*)tab16,
            (const float*)d_in[3], (const float*)d_in[5],
            (const float*)d_in[7], (const float*)d_in[9],
            (const float*)d_in[11], wpk,
            g_pos, g_dir, nullptr, nullptr, nullptr, nullptr, nullptr, 0);
        gather_enc2<<<8192, 256, 0, stream>>>(g_pos, g_tab, tab16, enc);
        nerf_mlp<<<NPTS / 256, 256, 0, stream>>>(
            g_dir, enc, wpk, nullptr, 0,
            (const float*)d_in[4], (const float*)d_in[6],
            (const float*)d_in[8], (const float*)d_in[10],
            (const float*)d_in[12],
            (float*)d_out);
    }
}